// Round 14
// baseline (361.085 us; speedup 1.0000x reference)
//
#include <hip/hip_runtime.h>

typedef short s16x8 __attribute__((ext_vector_type(8)));   // 8 bf16
typedef float f32x16 __attribute__((ext_vector_type(16))); // 32x32 MFMA acc

#define CODES_ELEMS 8388608   // 16*1024*512
#define N_ROWS      131072    // 16*1024*8
#define IDX_OFF     CODES_ELEMS
#define LOSS_OFF    (CODES_ELEMS + N_ROWS)

// d_ws: [0,4) loss acc; [64,8256) cc[2048];
// [8448,532736) cbs bf16-split tiled codebook [group64][frag8][lane64][8]
//   frag 0-3 = c1 dims 0..63, frag 4-7 = c2 (exact residual) dims 0..63
// [532736,532740) done2 completion counter
#define WS_LOSS 0
#define WS_CC   64
#define WS_CBS  8448
#define WS_DONE 532736
// validated r13-r22 (absmax 0 x10): packed-min + margin + offset constants
#define MARGIN_T 0.0625f
#define DIST_OFF 512.0f

__device__ __forceinline__ float bf2f(unsigned short h) { return __uint_as_float(((unsigned)h) << 16); }
__device__ __forceinline__ unsigned short f2bf(float f) {   // RNE
  unsigned u = __float_as_uint(f);
  u += 0x7fffu + ((u >> 16) & 1u);
  return (unsigned short)(u >> 16);
}

// Prep r23: SAME cbs values/layout as r13/r14 (32x32 B-frags, validated
// absmax 0) but vectorized: each thread produces one 16B fragment row
// (8 consecutive j) -> coalesced 256B stores per 16 threads. Blocks 0-127:
// convert (2048 codes x 16 slots). Blocks 128-159: cc[k] via the EXACT
// lane-d XOR-tree butterfly of r13-r22 (order-preserving; 16 codes/wave).
__global__ __launch_bounds__(256) void vq_prep(const float* __restrict__ cb,
                                               float* __restrict__ cc,
                                               unsigned short* __restrict__ cbs,
                                               float* __restrict__ loss,
                                               int* __restrict__ done2) {
  int t = threadIdx.x, b = blockIdx.x;
  if (b < 128) {
    int k = b * 16 + (t & 15);        // code
    int slot = t >> 4, f = slot >> 1, hi = slot & 1;
    int limb = f >> 2, dbase = (f & 3) * 16 + hi * 8;
    const float4* cb4 = (const float4*)cb;
    float4 u0 = cb4[k * 16 + (dbase >> 2)];
    float4 u1 = cb4[k * 16 + (dbase >> 2) + 1];
    float cj[8] = {u0.x, u0.y, u0.z, u0.w, u1.x, u1.y, u1.z, u1.w};
    s16x8 v;
    #pragma unroll
    for (int j = 0; j < 8; ++j) {
      unsigned short c1 = f2bf(cj[j]);
      v[j] = (short)(limb ? f2bf(cj[j] - bf2f(c1)) : c1);  // exact residual split
    }
    int g = k >> 5, n = k & 31;
    *(s16x8*)&cbs[(((size_t)g * 8 + f) * 64 + hi * 32 + n) * 8] = v;
  } else {
    if (b == 128 && t == 0) { loss[0] = 0.f; done2[0] = 0; }
    int w = t >> 6, l = t & 63;
    int k0 = (b - 128) * 64 + w * 16;   // 16 codes per wave
    for (int i = 0; i < 16; ++i) {
      int k = k0 + i;
      float c = cb[k * 64 + l];         // d = lane (order-preserving)
      float sq = c * c;
      #pragma unroll
      for (int m = 1; m < 64; m <<= 1) sq += __shfl_xor(sq, m, 64);
      if (l == 0) cc[k] = sq;
    }
  }
}

// Mega-kernel r23: 32x32x16 MFMA retry with the confounders removed.
// r13/r14's "32x32 spills" verdict was caused by the UNCAPPED tail unrolls
// (proven by r17: caps alone took 256->124 VGPR on the 16x16 version) — the
// shape itself was never tested with a sane tail. Mechanism: m119 shows
// dependent 32x32 chains self-pipeline at ~100% of MFMA peak; per group the
// loop runs 12 back-to-back 8-cyc MFMAs per 16 min-update VALU ops (half the
// VALU/code of 16x16). Structure: grid 1024, 128 rows/block, 4 waves x one
// 32-row tile, barrier-free global-B (r20-validated; chunk L1-resident),
// two 4-frag halves cap liveness (~115 VGPR -> 4 waves/SIMD). K-loop math =
// r14 (absmax 0); tail = r18 (absmax 0, caps); finalize fused via
// device-scope completion counter (2 launches total).
__global__ __launch_bounds__(256) void VQQuantizer_30064771072206_kernel(
    const float* __restrict__ zf, const float* __restrict__ cb,
    const unsigned short* __restrict__ cbs, const float* __restrict__ cc,
    float* __restrict__ loss, int* __restrict__ done2, float* __restrict__ out)
{
  __shared__ __align__(16) float cc_l[2048];     // 8KB, K-loop + rescore
  __shared__ int   idx_l[128];
  __shared__ int   flg[128];
  __shared__ int   nf;
  __shared__ __align__(16) float zl[8][68];
  __shared__ float zz_l[8];
  __shared__ int   rows_s[8];
  __shared__ float rv[4][8];
  __shared__ int   ri[4][8];
  __shared__ float wsum[4];

  const int t = threadIdx.x, w = t >> 6, l = t & 63;
  const int col = l & 31, hi = l >> 5;
  const int R0 = blockIdx.x * 128;
  const float4* zf4 = (const float4*)zf;
  const float4* cb4 = (const float4*)cb;

  // prologue: load full cc into LDS
  #pragma unroll
  for (int i = 0; i < 2; ++i)
    ((float4*)cc_l)[i * 256 + t] = ((const float4*)cc)[i * 256 + t];

  // A-frags (32x32x16, r14-validated): lane holds A[m=col][k=hi*8+j];
  // frag f covers dims f*16 + hi*8 + j. Row = R0 + w*32 + col.
  s16x8 az1[4], az2[4];   // [frag]: bf16(-2z) and exact residual
  {
    int row = R0 + w * 32 + col;
    const float4* zr = zf4 + (size_t)row * 16;
    #pragma unroll
    for (int f = 0; f < 4; ++f) {
      float4 u0 = zr[f * 4 + hi * 2];
      float4 u1 = zr[f * 4 + hi * 2 + 1];
      float m2[8] = {-2.f*u0.x, -2.f*u0.y, -2.f*u0.z, -2.f*u0.w,
                     -2.f*u1.x, -2.f*u1.y, -2.f*u1.z, -2.f*u1.w};
      #pragma unroll
      for (int j = 0; j < 8; ++j) {
        unsigned short h1 = f2bf(m2[j]);
        unsigned short h2 = f2bf(m2[j] - bf2f(h1));
        az1[f][j] = (short)h1;
        az2[f][j] = (short)h2;
      }
    }
  }

  unsigned p1[16], p2[16];   // packed (trunc dist | group-pid): best/second
  #pragma unroll
  for (int r = 0; r < 16; ++r) { p1[r] = 0xFFFFFFFFu; p2[r] = 0xFFFFFFFFu; }

  __syncthreads();   // cc_l visible (the ONLY barrier before phase 2)

  // ---- K-loop: barrier-free; 8 B-frags/group from L1/L2-resident cbs in
  // two 4-frag halves (liveness cap). MFMA order identical to r14.
  #pragma unroll 1
  for (int g = 0; g < 64; ++g) {
    const unsigned short* base = cbs + (size_t)g * 4096 + (size_t)l * 8;
    float nh = DIST_OFF + cc_l[g * 32 + col];
    unsigned pid = (unsigned)g;          // 6 bits, ascending codes
    f32x16 acc;
    #pragma unroll
    for (int r = 0; r < 16; ++r) acc[r] = nh;
    {
      s16x8 bc0 = *(const s16x8*)(base + 0 * 512);   // c1 frags
      s16x8 bc1 = *(const s16x8*)(base + 1 * 512);
      s16x8 bc2 = *(const s16x8*)(base + 2 * 512);
      s16x8 bc3 = *(const s16x8*)(base + 3 * 512);
      acc = __builtin_amdgcn_mfma_f32_32x32x16_bf16(az1[0], bc0, acc, 0, 0, 0);
      acc = __builtin_amdgcn_mfma_f32_32x32x16_bf16(az1[1], bc1, acc, 0, 0, 0);
      acc = __builtin_amdgcn_mfma_f32_32x32x16_bf16(az1[2], bc2, acc, 0, 0, 0);
      acc = __builtin_amdgcn_mfma_f32_32x32x16_bf16(az1[3], bc3, acc, 0, 0, 0);
      acc = __builtin_amdgcn_mfma_f32_32x32x16_bf16(az2[0], bc0, acc, 0, 0, 0);
      acc = __builtin_amdgcn_mfma_f32_32x32x16_bf16(az2[1], bc1, acc, 0, 0, 0);
      acc = __builtin_amdgcn_mfma_f32_32x32x16_bf16(az2[2], bc2, acc, 0, 0, 0);
      acc = __builtin_amdgcn_mfma_f32_32x32x16_bf16(az2[3], bc3, acc, 0, 0, 0);
    }
    {
      s16x8 bc4 = *(const s16x8*)(base + 4 * 512);   // c2 frags
      s16x8 bc5 = *(const s16x8*)(base + 5 * 512);
      s16x8 bc6 = *(const s16x8*)(base + 6 * 512);
      s16x8 bc7 = *(const s16x8*)(base + 7 * 512);
      acc = __builtin_amdgcn_mfma_f32_32x32x16_bf16(az1[0], bc4, acc, 0, 0, 0);
      acc = __builtin_amdgcn_mfma_f32_32x32x16_bf16(az1[1], bc5, acc, 0, 0, 0);
      acc = __builtin_amdgcn_mfma_f32_32x32x16_bf16(az1[2], bc6, acc, 0, 0, 0);
      acc = __builtin_amdgcn_mfma_f32_32x32x16_bf16(az1[3], bc7, acc, 0, 0, 0);
    }
    #pragma unroll
    for (int r = 0; r < 16; ++r) {   // packed (best, second): 4 int ops
      unsigned pd = (__float_as_uint(acc[r]) & 0xFFFFFF80u) | pid;
      unsigned mx = p1[r] > pd ? p1[r] : pd;
      p2[r] = p2[r] < mx ? p2[r] : mx;
      p1[r] = p1[r] < pd ? p1[r] : pd;
    }
  }

  // ---- phase 2: unpack + merge across the 32 lanes of each half (r14) ----
  if (t == 0) nf = 0;
  __syncthreads();
  #pragma unroll
  for (int r = 0; r < 16; ++r) {
    float a   = __uint_as_float(p1[r] & 0xFFFFFF80u);
    int   ia  = (int)(p1[r] & 127u) * 32 + col;   // code = pid*32 + col
    float b2v = __uint_as_float(p2[r] & 0xFFFFFF80u);
    #pragma unroll
    for (int m = 1; m < 32; m <<= 1) {   // halves hold different rows
      float oa = __shfl_xor(a, m, 64);
      int   oi = __shfl_xor(ia, m, 64);
      float ob = __shfl_xor(b2v, m, 64);
      float hv = fmaxf(a, oa);
      b2v = fminf(fminf(b2v, ob), hv);
      bool take = (oa < a) || (oa == a && oi < ia);
      a = take ? oa : a; ia = take ? oi : ia;
    }
    if (col == 0) {  // C/D: col=l&31, row=(r&3)+8*(r>>2)+4*(l>>5) [m74/m101]
      int rl = w * 32 + 4 * hi + (r & 3) + 8 * (r >> 2);
      idx_l[rl] = ia;
      if (b2v - a < MARGIN_T) {
        int p = atomicAdd(&nf, 1);
        flg[p] = rl;
      }
    }
  }
  __syncthreads();

  // ---- phase 3: exact fp32 rescore of flagged rows (r18-validated chain;
  //      dq-loop unroll capped at 4 to keep register pressure below K-loop) ----
  int count = nf;
  for (int itb = 0; itb * 8 < count; ++itb) {
    if (itb) __syncthreads();
    if (t < 8) {
      int ii = itb * 8 + t;
      rows_s[t] = flg[ii < count ? ii : count - 1];  // tail dup: benign rewrite
    }
    __syncthreads();
    if (t < 128) {
      int r = t >> 4, dq = t & 15;
      *(float4*)&zl[r][dq * 4] = zf4[(size_t)(R0 + rows_s[r]) * 16 + dq];
    }
    __syncthreads();
    if (t < 8) {                          // zz: sequential-d np chain
      float s = 0.f;
      for (int d = 0; d < 64; ++d) { float v = zl[t][d]; s += v * v; }
      zz_l[t] = s;
    }
    __syncthreads();

    float bv[8]; int bi[8];
    #pragma unroll
    for (int r = 0; r < 8; ++r) { bv[r] = 3.402823466e38f; bi[r] = 0; }
    #pragma unroll 1
    for (int o = 0; o < 8; ++o) {         // thread's codes ascending: o*256+t
      int c = o * 256 + t;
      const float4* cr = cb4 + (size_t)c * 16;
      float a[8];
      #pragma unroll
      for (int r = 0; r < 8; ++r) a[r] = 0.f;
      #pragma unroll 4                    // cap hoisted cv regs
      for (int dq = 0; dq < 16; ++dq) {
        float4 cv = cr[dq];
        #pragma unroll
        for (int r = 0; r < 8; ++r) {
          float4 z4 = *(const float4*)&zl[r][dq * 4];
          a[r] += z4.x * cv.x;
          a[r] += z4.y * cv.y;
          a[r] += z4.z * cv.z;
          a[r] += z4.w * cv.w;
        }
      }
      float ccv = cc_l[c];
      #pragma unroll
      for (int r = 0; r < 8; ++r) {
        float t0 = zz_l[r] - 2.0f * a[r];
        float dist = t0 + ccv;
        if (dist < bv[r]) { bv[r] = dist; bi[r] = c; }
      }
    }
    #pragma unroll
    for (int r = 0; r < 8; ++r) {
      float v = bv[r]; int idx = bi[r];
      #pragma unroll
      for (int m = 1; m < 64; m <<= 1) {
        float ov = __shfl_xor(v, m, 64); int oi = __shfl_xor(idx, m, 64);
        if (ov < v || (ov == v && oi < idx)) { v = ov; idx = oi; }
      }
      if (l == 0) { rv[w][r] = v; ri[w][r] = idx; }
    }
    __syncthreads();
    if (t < 8) {
      float fv = rv[0][t]; int fi = ri[0][t];
      #pragma unroll
      for (int k = 1; k < 4; ++k) {
        if (rv[k][t] < fv || (rv[k][t] == fv && ri[k][t] < fi)) { fv = rv[k][t]; fi = ri[k][t]; }
      }
      idx_l[rows_s[t]] = fi;
    }
  }
  __syncthreads();

  // ---- phase 4: epilogue for this block's 128 rows (unroll capped, r17) ----
  float4* out4 = (float4*)out;
  float lsum = 0.f;
  #pragma unroll 2
  for (int i = 0; i < 8; ++i) {
    int f = i * 256 + t;
    int row = f >> 4, dq = f & 15;
    int k = idx_l[row];
    float4 qv = cb4[(size_t)k * 16 + dq];
    float4 zv = zf4[(size_t)(R0 + row) * 16 + dq];
    float dx = qv.x - zv.x, dy = qv.y - zv.y, dz = qv.z - zv.z, dw = qv.w - zv.w;
    float4 st; st.x = zv.x + dx; st.y = zv.y + dy; st.z = zv.z + dz; st.w = zv.w + dw;
    out4[(size_t)(R0 + row) * 16 + dq] = st;
    lsum += dx * dx; lsum += dy * dy; lsum += dz * dz; lsum += dw * dw;
  }
  if (t < 128) out[IDX_OFF + R0 + t] = (float)idx_l[t];
  #pragma unroll
  for (int m = 1; m < 64; m <<= 1) lsum += __shfl_xor(lsum, m, 64);
  if (l == 0) wsum[w] = lsum;
  __syncthreads();
  // fused finalize: loss-add happens-before done2-add; 1024th arrival sees
  // all adds (device-scope atomics) and writes the scaled loss.
  if (t == 0) {
    atomicAdd(loss, wsum[0] + wsum[1] + wsum[2] + wsum[3]);
    __threadfence();
    int d = atomicAdd(done2, 1);
    if (d == 1023) {
      float total = atomicAdd(loss, 0.0f);   // RMW: serialized after all adds
      out[LOSS_OFF] = total * (1.f / 8388608.f);
    }
  }
}

extern "C" void kernel_launch(void* const* d_in, const int* in_sizes, int n_in,
                              void* d_out, int out_size, void* d_ws, size_t ws_size,
                              hipStream_t stream) {
  const float* z  = (const float*)d_in[0];
  const float* cb = (const float*)d_in[1];
  float* out = (float*)d_out;
  float* loss = (float*)((char*)d_ws + WS_LOSS);
  float* cc   = (float*)((char*)d_ws + WS_CC);
  unsigned short* cbs = (unsigned short*)((char*)d_ws + WS_CBS);
  int*   done2 = (int*)((char*)d_ws + WS_DONE);

  vq_prep<<<160, 256, 0, stream>>>(cb, cc, cbs, loss, done2);
  VQQuantizer_30064771072206_kernel<<<1024, 256, 0, stream>>>(z, cb, cbs, cc, loss, done2, out);
}

// Round 15
// 258.841 us; speedup vs baseline: 1.3950x; 1.3950x over previous
//
#include <hip/hip_runtime.h>

typedef short s16x8 __attribute__((ext_vector_type(8)));  // 8 bf16
typedef float f32x4 __attribute__((ext_vector_type(4)));  // 16x16 MFMA acc

#define CODES_ELEMS 8388608   // 16*1024*512
#define N_ROWS      131072    // 16*1024*8
#define IDX_OFF     CODES_ELEMS
#define LOSS_OFF    (CODES_ELEMS + N_ROWS)

// d_ws: [0,4) loss acc; [64,8256) cc[2048];
// [8448,532736) cbs bf16-split tiled codebook [chunk32][seg4][ct4][lane64][8]
//   seg 0,1 = c1 dims 0-31/32-63; seg 2,3 = c2 exact residual dims 0-31/32-63
// [532736,532740) done2 completion counter
#define WS_LOSS 0
#define WS_CC   64
#define WS_CBS  8448
#define WS_DONE 532736
// validated r13-r23 (absmax 0 x11): packed-min + margin + offset constants
#define MARGIN_T 0.0625f
#define DIST_OFF 512.0f

__device__ __forceinline__ float bf2f(unsigned short h) { return __uint_as_float(((unsigned)h) << 16); }
__device__ __forceinline__ unsigned short f2bf(float f) {   // RNE
  unsigned u = __float_as_uint(f);
  u += 0x7fffu + ((u >> 16) & 1u);
  return (unsigned short)(u >> 16);
}
// async global->LDS, 16B/lane; dest = wave-uniform base + lane*16
__device__ __forceinline__ void gl_lds16(const void* g, void* l) {
  __builtin_amdgcn_global_load_lds(
      (__attribute__((address_space(1))) void*)(g),
      (__attribute__((address_space(3))) void*)(l), 16, 0, 0);
}

// Prep r24: SAME cbs values/layout as r16/r17 (16x16 B-frags, validated
// absmax 0) but vectorized like r23's prep (validated): each thread emits one
// 16B fragment row (8 consecutive dims for fixed (k, s, q)) -> coalesced
// stores. Blocks 0-127: convert (2048 codes x 16 slots). Blocks 128-159:
// cc[k] via the EXACT lane-d XOR-tree butterfly (r23-validated, 16 codes/wave).
__global__ __launch_bounds__(256) void vq_prep(const float* __restrict__ cb,
                                               float* __restrict__ cc,
                                               unsigned short* __restrict__ cbs,
                                               float* __restrict__ loss,
                                               int* __restrict__ done2) {
  int t = threadIdx.x, b = blockIdx.x;
  if (b < 128) {
    int k = b * 16 + (t & 15);          // code
    int slot = t >> 4;                  // 16 slots = (s 0..3) x (q 0..3)
    int s = slot >> 2, q = slot & 3;
    int limb = s >> 1;                  // 0: c1, 1: exact residual
    int dbase = (s & 1) * 32 + q * 8;   // 8 consecutive dims
    const float4* cb4 = (const float4*)cb;
    float4 u0 = cb4[k * 16 + (dbase >> 2)];
    float4 u1 = cb4[k * 16 + (dbase >> 2) + 1];
    float cj[8] = {u0.x, u0.y, u0.z, u0.w, u1.x, u1.y, u1.z, u1.w};
    s16x8 v;
    #pragma unroll
    for (int j = 0; j < 8; ++j) {
      unsigned short c1 = f2bf(cj[j]);
      v[j] = (short)(limb ? f2bf(cj[j] - bf2f(c1)) : c1);  // exact residual split
    }
    int chunk = k >> 6, ct = (k >> 4) & 3, n = k & 15;
    *(s16x8*)&cbs[(((size_t)(chunk * 4 + s) * 4 + ct) * 64 + (q * 16 + n)) * 8] = v;
  } else {
    if (b == 128 && t == 0) { loss[0] = 0.f; done2[0] = 0; }
    int w = t >> 6, l = t & 63;
    int k0 = (b - 128) * 64 + w * 16;   // 16 codes per wave
    for (int i = 0; i < 16; ++i) {
      int k = k0 + i;
      float c = cb[k * 64 + l];         // d = lane (order-preserving butterfly)
      float sq = c * c;
      #pragma unroll
      for (int m = 1; m < 64; m <<= 1) sq += __shfl_xor(sq, m, 64);
      if (l == 0) cc[k] = sq;
    }
  }
}

// Mega-kernel r24 = r17's main VERBATIM (best measured: 185us, absmax 0,
// VGPR 124, zero spill, grid 512 x 256 rows, 4 tiles/wave, LDS-staged 16KB
// chunks, capped tail unrolls) + r23's validated fused-finalize pattern
// appended (device-scope done counter; 512th arrival writes scaled loss).
// r23's 32x32 retry was falsified (12% MfmaUtil, latency-bound chains);
// its aux structure (vectorized prep + 2 launches) saved ~36us and is kept.
__global__ __launch_bounds__(256) void VQQuantizer_30064771072206_kernel(
    const float* __restrict__ zf, const float* __restrict__ cb,
    const unsigned short* __restrict__ cbs, const float* __restrict__ cc,
    float* __restrict__ loss, int* __restrict__ done2, float* __restrict__ out)
{
  __shared__ __align__(16) unsigned short bt[2][8192];   // 2 x 16KB: [seg4][ct4][lane64][8]
  __shared__ __align__(16) float cc_l[2048];
  // ---- tail arena aliased onto bt (only touched after the K-loop) ----
  int*   idx_l  = (int*)&bt[0][0];                        // 256 ints  [0,1024)
  int*   flg    = (int*)((char*)&bt[0][0] + 1024);        // 256 ints  [1024,2048)
  int*   nf     = (int*)((char*)&bt[0][0] + 2048);        // [2048,2052)
  float (*zl)[68] = (float(*)[68])((char*)&bt[0][0] + 2064);  // 8*68 f
  float* zz_l   = (float*)((char*)&bt[0][0] + 4240);      // 8 f
  int*   rows_s = (int*)((char*)&bt[0][0] + 4272);        // 8 i
  float (*rv)[8] = (float(*)[8])((char*)&bt[0][0] + 4304); // 4x8 f
  int   (*ri)[8] = (int(*)[8])((char*)&bt[0][0] + 4432);   // 4x8 i
  float* wsum   = (float*)((char*)&bt[0][0] + 4560);      // 4 f

  const int t = threadIdx.x, w = t >> 6, l = t & 63;
  const int col = l & 15, q = l >> 4;
  const int R0 = blockIdx.x * 256;
  const float4* zf4 = (const float4*)zf;
  const float4* cb4 = (const float4*)cb;

  // prologue: stage chunk 0 (16KB) into buf 0; load full cc
  #pragma unroll
  for (int i = 0; i < 4; ++i) {
    int s0 = i * 256 + w * 64;            // wave-uniform 16B-slot base
    gl_lds16(cbs + (size_t)(s0 + l) * 8, &bt[0][(size_t)s0 * 8]);
  }
  #pragma unroll
  for (int i = 0; i < 2; ++i)
    ((float4*)cc_l)[i * 256 + t] = ((const float4*)cc)[i * 256 + t];

  // A-fragments (r12-validated): lane holds A[m=l&15][k=q*8+j]; per tile
  // row = R0 + tile*64 + 16w + col; seg s covers dims s*32 + q*8 + j.
  s16x8 az1[4][2], az2[4][2];   // [tile][seg]: bf16(-2z) and exact residual
  #pragma unroll
  for (int tile = 0; tile < 4; ++tile) {
    int row = R0 + tile * 64 + 16 * w + col;
    const float4* zr = zf4 + (size_t)row * 16;
    #pragma unroll
    for (int s = 0; s < 2; ++s) {
      float4 u0 = zr[s * 8 + q * 2];
      float4 u1 = zr[s * 8 + q * 2 + 1];
      float m2[8] = {-2.f*u0.x, -2.f*u0.y, -2.f*u0.z, -2.f*u0.w,
                     -2.f*u1.x, -2.f*u1.y, -2.f*u1.z, -2.f*u1.w};
      #pragma unroll
      for (int j = 0; j < 8; ++j) {
        unsigned short h1 = f2bf(m2[j]);
        unsigned short h2 = f2bf(m2[j] - bf2f(h1));
        az1[tile][s][j] = (short)h1;
        az2[tile][s][j] = (short)h2;
      }
    }
  }

  unsigned p1[4][4], p2[4][4];   // packed (trunc dist | pid): best / second
  #pragma unroll
  for (int tile = 0; tile < 4; ++tile)
    #pragma unroll
    for (int r = 0; r < 4; ++r) { p1[tile][r] = 0xFFFFFFFFu; p2[tile][r] = 0xFFFFFFFFu; }

  __syncthreads();   // drains prologue stage + cc_l writes

  int cur = 0;
  for (int chunk = 0; chunk < 32; ++chunk) {
    if (chunk + 1 < 32) {            // prefetch next chunk into buf^1
      const unsigned short* src = cbs + (size_t)(chunk + 1) * 8192;
      unsigned short* dst = &bt[cur ^ 1][0];
      #pragma unroll
      for (int i = 0; i < 4; ++i) {
        int s0 = i * 256 + w * 64;
        gl_lds16(src + (size_t)(s0 + l) * 8, dst + (size_t)s0 * 8);
      }
    }
    const unsigned short* bb = &bt[cur][l * 8];
    const float* ccc = &cc_l[chunk * 64 + col];
    #pragma unroll
    for (int ct = 0; ct < 4; ++ct) {
      float nh = DIST_OFF + ccc[ct * 16];
      const unsigned short* base = bb + ct * 512;
      s16x8 b0 = *(const s16x8*)(base + 0 * 2048);   // c1 dims 0-31
      s16x8 b1 = *(const s16x8*)(base + 1 * 2048);   // c1 dims 32-63
      s16x8 b2 = *(const s16x8*)(base + 2 * 2048);   // c2 dims 0-31
      s16x8 b3 = *(const s16x8*)(base + 3 * 2048);   // c2 dims 32-63
      unsigned pid = (unsigned)(chunk * 4 + ct);     // 7 bits, ascending codes
      #pragma unroll
      for (int tile = 0; tile < 4; ++tile) {
        f32x4 acc; acc[0] = nh; acc[1] = nh; acc[2] = nh; acc[3] = nh;
        acc = __builtin_amdgcn_mfma_f32_16x16x32_bf16(az1[tile][0], b0, acc, 0, 0, 0);
        acc = __builtin_amdgcn_mfma_f32_16x16x32_bf16(az1[tile][1], b1, acc, 0, 0, 0);
        acc = __builtin_amdgcn_mfma_f32_16x16x32_bf16(az1[tile][0], b2, acc, 0, 0, 0);
        acc = __builtin_amdgcn_mfma_f32_16x16x32_bf16(az1[tile][1], b3, acc, 0, 0, 0);
        acc = __builtin_amdgcn_mfma_f32_16x16x32_bf16(az2[tile][0], b0, acc, 0, 0, 0);
        acc = __builtin_amdgcn_mfma_f32_16x16x32_bf16(az2[tile][1], b1, acc, 0, 0, 0);
        #pragma unroll
        for (int r = 0; r < 4; ++r) {   // packed (best, second): 4 int ops
          unsigned pd = (__float_as_uint(acc[r]) & 0xFFFFFF80u) | pid;
          unsigned mx = p1[tile][r] > pd ? p1[tile][r] : pd;
          p2[tile][r] = p2[tile][r] < mx ? p2[tile][r] : mx;
          p1[tile][r] = p1[tile][r] < pd ? p1[tile][r] : pd;
        }
      }
    }
    __syncthreads();   // readers done with cur; prefetch landed in cur^1
    cur ^= 1;
  }

  // ---- phase 2: unpack + merge across the 16 lanes of each row group ----
  if (t == 0) *nf = 0;
  __syncthreads();     // bt dead; arena live from here
  #pragma unroll
  for (int tile = 0; tile < 4; ++tile) {
    #pragma unroll
    for (int r = 0; r < 4; ++r) {
      float a   = __uint_as_float(p1[tile][r] & 0xFFFFFF80u);
      int   ia  = (int)(p1[tile][r] & 127u) * 16 + col;   // code = pid*16 + col
      float b2v = __uint_as_float(p2[tile][r] & 0xFFFFFF80u);
      #pragma unroll
      for (int m = 1; m < 16; m <<= 1) {
        float oa = __shfl_xor(a, m, 64);
        int   oi = __shfl_xor(ia, m, 64);
        float ob = __shfl_xor(b2v, m, 64);
        float hv = fmaxf(a, oa);
        b2v = fminf(fminf(b2v, ob), hv);
        bool take = (oa < a) || (oa == a && oi < ia);
        a = take ? oa : a; ia = take ? oi : ia;
      }
      if (col == 0) {   // C/D: col=l&15, row=(l>>4)*4+r [m89, validated]
        int rl = tile * 64 + 16 * w + q * 4 + r;
        idx_l[rl] = ia;
        if (b2v - a < MARGIN_T) {
          int p = atomicAdd(nf, 1);
          flg[p] = rl;
        }
      }
    }
  }
  __syncthreads();

  // ---- phase 3: exact fp32 rescore of flagged rows (validated inner chain;
  //      dq-loop unroll capped at 4 to keep register pressure below K-loop) ----
  int count = *nf;
  for (int itb = 0; itb * 8 < count; ++itb) {
    if (itb) __syncthreads();
    if (t < 8) {
      int ii = itb * 8 + t;
      rows_s[t] = flg[ii < count ? ii : count - 1];  // tail dup: benign rewrite
    }
    __syncthreads();
    if (t < 128) {
      int r = t >> 4, dq = t & 15;
      *(float4*)&zl[r][dq * 4] = zf4[(size_t)(R0 + rows_s[r]) * 16 + dq];
    }
    __syncthreads();
    if (t < 8) {                          // zz: sequential-d np chain
      float s = 0.f;
      for (int d = 0; d < 64; ++d) { float v = zl[t][d]; s += v * v; }
      zz_l[t] = s;
    }
    __syncthreads();

    float bv[8]; int bi[8];
    #pragma unroll
    for (int r = 0; r < 8; ++r) { bv[r] = 3.402823466e38f; bi[r] = 0; }
    #pragma unroll 1
    for (int o = 0; o < 8; ++o) {         // thread's codes ascending: o*256+t
      int c = o * 256 + t;
      const float4* cr = cb4 + (size_t)c * 16;
      float a[8];
      #pragma unroll
      for (int r = 0; r < 8; ++r) a[r] = 0.f;
      #pragma unroll 4                    // cap hoisted cv regs
      for (int dq = 0; dq < 16; ++dq) {
        float4 cv = cr[dq];
        #pragma unroll
        for (int r = 0; r < 8; ++r) {
          float4 z4 = *(const float4*)&zl[r][dq * 4];
          a[r] += z4.x * cv.x;
          a[r] += z4.y * cv.y;
          a[r] += z4.z * cv.z;
          a[r] += z4.w * cv.w;
        }
      }
      float ccv = cc_l[c];
      #pragma unroll
      for (int r = 0; r < 8; ++r) {
        float t0 = zz_l[r] - 2.0f * a[r];
        float dist = t0 + ccv;
        if (dist < bv[r]) { bv[r] = dist; bi[r] = c; }
      }
    }
    #pragma unroll
    for (int r = 0; r < 8; ++r) {
      float v = bv[r]; int idx = bi[r];
      #pragma unroll
      for (int m = 1; m < 64; m <<= 1) {
        float ov = __shfl_xor(v, m, 64); int oi = __shfl_xor(idx, m, 64);
        if (ov < v || (ov == v && oi < idx)) { v = ov; idx = oi; }
      }
      if (l == 0) { rv[w][r] = v; ri[w][r] = idx; }
    }
    __syncthreads();
    if (t < 8) {
      float fv = rv[0][t]; int fi = ri[0][t];
      #pragma unroll
      for (int k = 1; k < 4; ++k) {
        if (rv[k][t] < fv || (rv[k][t] == fv && ri[k][t] < fi)) { fv = rv[k][t]; fi = ri[k][t]; }
      }
      idx_l[rows_s[t]] = fi;
    }
  }
  __syncthreads();

  // ---- phase 4: epilogue for this block's 256 rows (unroll capped, r17) ----
  float4* out4 = (float4*)out;
  float lsum = 0.f;
  #pragma unroll 2
  for (int i = 0; i < 16; ++i) {
    int f = i * 256 + t;
    int row = f >> 4, dq = f & 15;
    int k = idx_l[row];
    float4 qv = cb4[(size_t)k * 16 + dq];
    float4 zv = zf4[(size_t)(R0 + row) * 16 + dq];
    float dx = qv.x - zv.x, dy = qv.y - zv.y, dz = qv.z - zv.z, dw = qv.w - zv.w;
    float4 st; st.x = zv.x + dx; st.y = zv.y + dy; st.z = zv.z + dz; st.w = zv.w + dw;
    out4[(size_t)(R0 + row) * 16 + dq] = st;
    lsum += dx * dx; lsum += dy * dy; lsum += dz * dz; lsum += dw * dw;
  }
  out[IDX_OFF + R0 + t] = (float)idx_l[t];
  #pragma unroll
  for (int m = 1; m < 64; m <<= 1) lsum += __shfl_xor(lsum, m, 64);
  if (l == 0) wsum[w] = lsum;
  __syncthreads();
  // fused finalize (r23-validated): loss-add happens-before done2-add; the
  // 512th arrival sees all adds (device-scope) and writes the scaled loss.
  if (t == 0) {
    atomicAdd(loss, wsum[0] + wsum[1] + wsum[2] + wsum[3]);
    __threadfence();
    int d = atomicAdd(done2, 1);
    if (d == 511) {
      float total = atomicAdd(loss, 0.0f);   // RMW: serialized after all adds
      out[LOSS_OFF] = total * (1.f / 8388608.f);
    }
  }
}

extern "C" void kernel_launch(void* const* d_in, const int* in_sizes, int n_in,
                              void* d_out, int out_size, void* d_ws, size_t ws_size,
                              hipStream_t stream) {
  const float* z  = (const float*)d_in[0];
  const float* cb = (const float*)d_in[1];
  float* out = (float*)d_out;
  float* loss = (float*)((char*)d_ws + WS_LOSS);
  float* cc   = (float*)((char*)d_ws + WS_CC);
  unsigned short* cbs = (unsigned short*)((char*)d_ws + WS_CBS);
  int*   done2 = (int*)((char*)d_ws + WS_DONE);

  vq_prep<<<160, 256, 0, stream>>>(cb, cc, cbs, loss, done2);
  VQQuantizer_30064771072206_kernel<<<512, 256, 0, stream>>>(z, cb, cbs, cc, loss, done2, out);
}